// Round 1
// baseline (131.852 us; speedup 1.0000x reference)
//
#include <hip/hip_runtime.h>
#include <math.h>

#define NN 1024
#define DIN 6
#define DI 16
#define DE 64

// ws layout (in floats)
#define OFF_QI 0
#define OFF_KI (OFF_QI + NN*DI)
#define OFF_QE (OFF_KI + NN*DI)
#define OFF_KR (OFF_QE + NN*DE)
#define OFF_KV (OFF_KR + NN*DE)
#define OFF_VR (OFF_KV + NN*DE)
#define OFF_VV (OFF_VR + NN*DE)
#define OFF_GR (OFF_VV + NN*DE)
#define OFF_GV (OFF_GR + NN)
// total floats = OFF_GV + NN = 362496 -> 1.45 MB

__global__ __launch_bounds__(256) void nce_precompute(
    const float* __restrict__ nc,
    const float* __restrict__ Wq_i, const float* __restrict__ Wk_i,
    const float* __restrict__ Wv_i, const float* __restrict__ Wq_e,
    const float* __restrict__ Wk_e, const float* __restrict__ Wv_e,
    const float* __restrict__ wg, float* __restrict__ ws)
{
    int n = blockIdx.x * blockDim.x + threadIdx.x;
    if (n >= NN) return;

    float x[DIN];
    #pragma unroll
    for (int f = 0; f < DIN; ++f) x[f] = nc[n*DIN + f];

    float vi[DI];
    #pragma unroll
    for (int j = 0; j < DI; ++j) {
        float qi = 0.f, ki = 0.f, vv = 0.f;
        #pragma unroll
        for (int f = 0; f < DIN; ++f) {
            qi += x[f] * Wq_i[f*DI + j];
            ki += x[f] * Wk_i[f*DI + j];
            vv += x[f] * Wv_i[f*DI + j];
        }
        ws[OFF_QI + n*DI + j] = qi;
        ws[OFF_KI + n*DI + j] = ki;
        vi[j] = vv;
    }

    float gr = 0.f, gv = 0.f;
    #pragma unroll 4
    for (int d = 0; d < DE; ++d) {
        float qe = 0.f, kr = 0.f, vr = 0.f;
        #pragma unroll
        for (int f = 0; f < DIN; ++f) {
            qe += x[f] * Wq_e[f*DE + d];
            kr += x[f] * Wk_e[f*DE + d];
            vr += x[f] * Wv_e[f*DE + d];
        }
        float kv = 0.f, vv = 0.f;
        #pragma unroll
        for (int j = 0; j < DI; ++j) {
            kv += vi[j] * Wk_e[(DIN + j)*DE + d];
            vv += vi[j] * Wv_e[(DIN + j)*DE + d];
        }
        ws[OFF_QE + n*DE + d] = qe;
        ws[OFF_KR + n*DE + d] = kr;
        ws[OFF_KV + n*DE + d] = kv;
        ws[OFF_VR + n*DE + d] = vr;
        ws[OFF_VV + n*DE + d] = vv;
        float w = wg[d];
        gr += vr * w;
        gv += vv * w;
    }
    ws[OFF_GR + n] = gr;
    ws[OFF_GV + n] = gv;
}

__device__ __forceinline__ float blk_reduce(float v, bool is_max, float* s_red, int tid)
{
    #pragma unroll
    for (int off = 32; off > 0; off >>= 1) {
        float o = __shfl_xor(v, off, 64);
        v = is_max ? fmaxf(v, o) : (v + o);
    }
    if ((tid & 63) == 0) s_red[tid >> 6] = v;
    __syncthreads();
    float r = is_max ? fmaxf(fmaxf(s_red[0], s_red[1]), fmaxf(s_red[2], s_red[3]))
                     : (s_red[0] + s_red[1]) + (s_red[2] + s_red[3]);
    __syncthreads();
    return r;
}

__global__ __launch_bounds__(256) void nce_centre(
    const float* __restrict__ ws,
    const float* __restrict__ bgp,
    float* __restrict__ out)
{
    const int c = blockIdx.x;
    const int tid = threadIdx.x;

    __shared__ float s_qi[DI];
    __shared__ float s_qe[DE];
    __shared__ float s_w1[NN];
    __shared__ float s_w2[NN];
    __shared__ float s_red[4];
    __shared__ float s_part[4][DE];

    if (tid < DI) s_qi[tid] = ws[OFF_QI + c*DI + tid];
    if (tid < DE) s_qe[tid] = ws[OFF_QE + c*DE + tid];
    __syncthreads();

    // ---- stage 1: a_i[c, n] softmax over n (each thread owns 4 nodes) ----
    float si[4];
    float lmax = -1e30f;
    #pragma unroll
    for (int j = 0; j < 4; ++j) {
        int n = tid + 256*j;
        const float* ki = ws + OFF_KI + n*DI;
        float s = 0.f;
        #pragma unroll
        for (int q = 0; q < DI; ++q) s += s_qi[q] * ki[q];
        si[j] = s * 0.25f;                  // 1/sqrt(16)
        lmax = fmaxf(lmax, si[j]);
    }
    float m1 = blk_reduce(lmax, true, s_red, tid);
    float e1[4];
    float lsum = 0.f;
    #pragma unroll
    for (int j = 0; j < 4; ++j) { e1[j] = expf(si[j] - m1); lsum += e1[j]; }
    float inv1 = 1.f / blk_reduce(lsum, false, s_red, tid);
    float ai[4];
    #pragma unroll
    for (int j = 0; j < 4; ++j) ai[j] = e1[j] * inv1;

    // ---- stage 2: scores_e = (Qe·Kr[n] + a_i*(Qe·Kv[n])) / 8, softmax ----
    const float4* qe4 = (const float4*)s_qe;
    float se[4];
    lmax = -1e30f;
    #pragma unroll
    for (int j = 0; j < 4; ++j) {
        int n = tid + 256*j;
        const float4* kr = (const float4*)(ws + OFF_KR + n*DE);
        const float4* kv = (const float4*)(ws + OFF_KV + n*DE);
        float s1 = 0.f, s2 = 0.f;
        #pragma unroll
        for (int q = 0; q < DE/4; ++q) {
            float4 qv = qe4[q];
            float4 a = kr[q];
            float4 b = kv[q];
            s1 += qv.x*a.x + qv.y*a.y + qv.z*a.z + qv.w*a.w;
            s2 += qv.x*b.x + qv.y*b.y + qv.z*b.z + qv.w*b.w;
        }
        se[j] = (s1 + ai[j]*s2) * 0.125f;   // 1/sqrt(64)
        lmax = fmaxf(lmax, se[j]);
    }
    float m2 = blk_reduce(lmax, true, s_red, tid);
    float e2[4];
    lsum = 0.f;
    #pragma unroll
    for (int j = 0; j < 4; ++j) { e2[j] = expf(se[j] - m2); lsum += e2[j]; }
    float inv2 = 1.f / blk_reduce(lsum, false, s_red, tid);

    const float bg = *bgp;
    #pragma unroll
    for (int j = 0; j < 4; ++j) {
        int n = tid + 256*j;
        float ae = e2[j] * inv2;
        float pre = ae * (ws[OFF_GR + n] + ai[j] * ws[OFF_GV + n]) + bg;
        float g = 1.f / (1.f + expf(-pre));
        float w1 = g * ae;
        s_w1[n] = w1;
        s_w2[n] = w1 * ai[j];
    }
    __syncthreads();

    // ---- stage 3: out[c,:] = w1 @ Vr + w2 @ Vv ----
    const int d = tid & 63;
    const int chunk = tid >> 6;
    const float* vr = ws + OFF_VR + (chunk*256)*DE + d;
    const float* vv = ws + OFF_VV + (chunk*256)*DE + d;
    float acc = 0.f;
    #pragma unroll 4
    for (int i = 0; i < 256; ++i) {
        int n = chunk*256 + i;
        acc += s_w1[n] * vr[i*DE] + s_w2[n] * vv[i*DE];
    }
    s_part[chunk][d] = acc;
    __syncthreads();
    if (tid < DE) {
        out[c*DE + tid] = (s_part[0][tid] + s_part[1][tid])
                        + (s_part[2][tid] + s_part[3][tid]);
    }
}

extern "C" void kernel_launch(void* const* d_in, const int* in_sizes, int n_in,
                              void* d_out, int out_size, void* d_ws, size_t ws_size,
                              hipStream_t stream)
{
    const float* nc   = (const float*)d_in[0];
    const float* Wq_i = (const float*)d_in[1];
    const float* Wk_i = (const float*)d_in[2];
    const float* Wv_i = (const float*)d_in[3];
    const float* Wq_e = (const float*)d_in[4];
    const float* Wk_e = (const float*)d_in[5];
    const float* Wv_e = (const float*)d_in[6];
    const float* wg   = (const float*)d_in[7];
    const float* bg   = (const float*)d_in[8];
    float* out = (float*)d_out;
    float* ws  = (float*)d_ws;

    nce_precompute<<<NN/256, 256, 0, stream>>>(nc, Wq_i, Wk_i, Wv_i,
                                               Wq_e, Wk_e, Wv_e, wg, ws);
    nce_centre<<<NN, 256, 0, stream>>>(ws, bg, out);
}

// Round 2
// 52.131 us; speedup vs baseline: 2.5293x; 2.5293x over previous
//
#include <hip/hip_runtime.h>
#include <math.h>

#define NN 1024
#define DIN 6
#define DI 16
#define DE 64
#define GC 8              // centres per block
#define NT 512            // threads per centre-block
#define NWAVE (NT/64)     // 8
#define NBLK (NN/GC)      // 128

// ws layout (floats)
#define OFF_QI 0
#define OFF_KI (OFF_QI + NN*DI)
#define OFF_QE (OFF_KI + NN*DI)
#define OFF_KR (OFF_QE + NN*DE)
#define OFF_KV (OFF_KR + NN*DE)
#define OFF_VR (OFF_KV + NN*DE)
#define OFF_VV (OFF_VR + NN*DE)
#define OFF_GR (OFF_VV + NN*DE)
#define OFF_GV (OFF_GR + NN)

__global__ __launch_bounds__(256) void nce_precompute(
    const float* __restrict__ nc,
    const float* __restrict__ Wq_i, const float* __restrict__ Wk_i,
    const float* __restrict__ Wv_i, const float* __restrict__ Wq_e,
    const float* __restrict__ Wk_e, const float* __restrict__ Wv_e,
    const float* __restrict__ wg, float* __restrict__ ws)
{
    const int s    = threadIdx.x >> 6;     // node sub-index within block
    const int lane = threadIdx.x & 63;     // = encoding dim d
    const int n    = blockIdx.x * 4 + s;
    __shared__ float s_vi[4][DI];

    float x[DIN];
    #pragma unroll
    for (int f = 0; f < DIN; ++f) x[f] = nc[n*DIN + f];

    if (lane < DI) {
        float qi = 0.f, ki = 0.f, vv = 0.f;
        #pragma unroll
        for (int f = 0; f < DIN; ++f) {
            qi += x[f] * Wq_i[f*DI + lane];
            ki += x[f] * Wk_i[f*DI + lane];
            vv += x[f] * Wv_i[f*DI + lane];
        }
        ws[OFF_QI + n*DI + lane] = qi;
        ws[OFF_KI + n*DI + lane] = ki;
        s_vi[s][lane] = vv;
    }
    __syncthreads();

    float qe = 0.f, kr = 0.f, vr = 0.f;
    #pragma unroll
    for (int f = 0; f < DIN; ++f) {
        qe += x[f] * Wq_e[f*DE + lane];
        kr += x[f] * Wk_e[f*DE + lane];
        vr += x[f] * Wv_e[f*DE + lane];
    }
    float kv = 0.f, vv2 = 0.f;
    #pragma unroll
    for (int j = 0; j < DI; ++j) {
        float v = s_vi[s][j];
        kv  += v * Wk_e[(DIN+j)*DE + lane];
        vv2 += v * Wv_e[(DIN+j)*DE + lane];
    }
    ws[OFF_QE + n*DE + lane] = qe;
    ws[OFF_KR + n*DE + lane] = kr;
    ws[OFF_KV + n*DE + lane] = kv;
    ws[OFF_VR + n*DE + lane] = vr;
    ws[OFF_VV + n*DE + lane] = vv2;

    float w   = wg[lane];
    float grt = vr * w, gvt = vv2 * w;
    #pragma unroll
    for (int off = 32; off > 0; off >>= 1) {
        grt += __shfl_xor(grt, off, 64);
        gvt += __shfl_xor(gvt, off, 64);
    }
    if (lane == 0) { ws[OFF_GR + n] = grt; ws[OFF_GV + n] = gvt; }
}

__device__ __forceinline__ float dot4(float4 a, float4 b) {
    return a.x*b.x + a.y*b.y + a.z*b.z + a.w*b.w;
}

template<bool IS_MAX>
__device__ __forceinline__ void blk_red(float v[GC], float (*s_red)[NWAVE],
                                        int wave, int lane)
{
    #pragma unroll
    for (int c = 0; c < GC; ++c) {
        #pragma unroll
        for (int off = 32; off > 0; off >>= 1) {
            float o = __shfl_xor(v[c], off, 64);
            v[c] = IS_MAX ? fmaxf(v[c], o) : v[c] + o;
        }
    }
    if (lane == 0) {
        #pragma unroll
        for (int c = 0; c < GC; ++c) s_red[c][wave] = v[c];
    }
    __syncthreads();
    #pragma unroll
    for (int c = 0; c < GC; ++c) {
        float r = s_red[c][0];
        #pragma unroll
        for (int w = 1; w < NWAVE; ++w)
            r = IS_MAX ? fmaxf(r, s_red[c][w]) : r + s_red[c][w];
        v[c] = r;
    }
    __syncthreads();
}

__global__ __launch_bounds__(NT) void nce_centre(
    const float* __restrict__ ws, const float* __restrict__ bgp,
    float* __restrict__ out)
{
    const int c0   = blockIdx.x * GC;
    const int tid  = threadIdx.x;
    const int wave = tid >> 6;
    const int lane = tid & 63;

    __shared__ float4 s_qi4[GC][DI/4];      // 512 B
    __shared__ float4 s_qe4[GC][DE/4];      // 2 KB
    __shared__ float  s_red[GC][NWAVE];     // 256 B
    __shared__ float4 s_w1p[2][NN];         // 32 KB  (w1 packed 4 centres/float4)
    __shared__ float4 s_w2p[2][NN];         // 32 KB
    __shared__ float  s_part[NWAVE][GC][DE];// 16 KB

    if (tid < GC*DI) ((float*)s_qi4)[tid] = ws[OFF_QI + c0*DI + tid];
    ((float*)s_qe4)[tid] = ws[OFF_QE + c0*DE + tid];   // NT == GC*DE
    __syncthreads();

    const int nA = tid, nB = tid + NT;

    // ---------------- stage 1: a_i softmax ----------------
    float sA[GC], sB[GC];
    #pragma unroll
    for (int c = 0; c < GC; ++c) { sA[c] = 0.f; sB[c] = 0.f; }
    {
        const float4* kiA = (const float4*)(ws + OFF_KI + nA*DI);
        const float4* kiB = (const float4*)(ws + OFF_KI + nB*DI);
        #pragma unroll
        for (int q = 0; q < DI/4; ++q) {
            float4 a = kiA[q], b = kiB[q];
            #pragma unroll
            for (int c = 0; c < GC; ++c) {
                float4 qv = s_qi4[c][q];
                sA[c] += dot4(qv, a);
                sB[c] += dot4(qv, b);
            }
        }
    }
    float red[GC];
    #pragma unroll
    for (int c = 0; c < GC; ++c) {
        sA[c] *= 0.25f; sB[c] *= 0.25f;          // 1/sqrt(16)
        red[c] = fmaxf(sA[c], sB[c]);
    }
    blk_red<true>(red, s_red, wave, lane);
    float aiA[GC], aiB[GC];
    #pragma unroll
    for (int c = 0; c < GC; ++c) {
        aiA[c] = __expf(sA[c] - red[c]);
        aiB[c] = __expf(sB[c] - red[c]);
        red[c] = aiA[c] + aiB[c];
    }
    blk_red<false>(red, s_red, wave, lane);
    #pragma unroll
    for (int c = 0; c < GC; ++c) {
        float inv = 1.f / red[c];
        aiA[c] *= inv; aiB[c] *= inv;
    }

    // ---------------- stage 2: scores_e softmax + gate ----------------
    float s1A[GC], s2A[GC], s1B[GC], s2B[GC];
    #pragma unroll
    for (int c = 0; c < GC; ++c) { s1A[c]=0.f; s2A[c]=0.f; s1B[c]=0.f; s2B[c]=0.f; }
    {
        const float4* krA = (const float4*)(ws + OFF_KR + nA*DE);
        const float4* kvA = (const float4*)(ws + OFF_KV + nA*DE);
        const float4* krB = (const float4*)(ws + OFF_KR + nB*DE);
        const float4* kvB = (const float4*)(ws + OFF_KV + nB*DE);
        #pragma unroll
        for (int q = 0; q < DE/4; ++q) {
            float4 a = krA[q], b = kvA[q], e = krB[q], f = kvB[q];
            #pragma unroll
            for (int c = 0; c < GC; ++c) {
                float4 qv = s_qe4[c][q];
                s1A[c] += dot4(qv, a); s2A[c] += dot4(qv, b);
                s1B[c] += dot4(qv, e); s2B[c] += dot4(qv, f);
            }
        }
    }
    #pragma unroll
    for (int c = 0; c < GC; ++c) {
        sA[c] = (s1A[c] + aiA[c]*s2A[c]) * 0.125f;   // 1/sqrt(64)
        sB[c] = (s1B[c] + aiB[c]*s2B[c]) * 0.125f;
        red[c] = fmaxf(sA[c], sB[c]);
    }
    blk_red<true>(red, s_red, wave, lane);
    float eA[GC], eB[GC];
    #pragma unroll
    for (int c = 0; c < GC; ++c) {
        eA[c] = __expf(sA[c] - red[c]);
        eB[c] = __expf(sB[c] - red[c]);
        red[c] = eA[c] + eB[c];
    }
    blk_red<false>(red, s_red, wave, lane);

    const float bg  = *bgp;
    const float grA = ws[OFF_GR + nA], gvA = ws[OFF_GV + nA];
    const float grB = ws[OFF_GR + nB], gvB = ws[OFF_GV + nB];
    float w1A[GC], w2A[GC], w1B[GC], w2B[GC];
    #pragma unroll
    for (int c = 0; c < GC; ++c) {
        float inv = 1.f / red[c];
        float aeA = eA[c]*inv, aeB = eB[c]*inv;
        float preA = aeA*(grA + aiA[c]*gvA) + bg;
        float preB = aeB*(grB + aiB[c]*gvB) + bg;
        float gA = 1.f / (1.f + __expf(-preA));
        float gB = 1.f / (1.f + __expf(-preB));
        w1A[c] = gA*aeA; w2A[c] = w1A[c]*aiA[c];
        w1B[c] = gB*aeB; w2B[c] = w1B[c]*aiB[c];
    }
    s_w1p[0][nA] = make_float4(w1A[0], w1A[1], w1A[2], w1A[3]);
    s_w1p[1][nA] = make_float4(w1A[4], w1A[5], w1A[6], w1A[7]);
    s_w2p[0][nA] = make_float4(w2A[0], w2A[1], w2A[2], w2A[3]);
    s_w2p[1][nA] = make_float4(w2A[4], w2A[5], w2A[6], w2A[7]);
    s_w1p[0][nB] = make_float4(w1B[0], w1B[1], w1B[2], w1B[3]);
    s_w1p[1][nB] = make_float4(w1B[4], w1B[5], w1B[6], w1B[7]);
    s_w2p[0][nB] = make_float4(w2B[0], w2B[1], w2B[2], w2B[3]);
    s_w2p[1][nB] = make_float4(w2B[4], w2B[5], w2B[6], w2B[7]);
    __syncthreads();

    // ---------------- stage 3: out = w1@Vr + w2@Vv ----------------
    float acc[GC];
    #pragma unroll
    for (int c = 0; c < GC; ++c) acc[c] = 0.f;
    const int nbase = wave * (NN/NWAVE);          // 128 nodes per wave
    const float* vr = ws + OFF_VR + nbase*DE + lane;
    const float* vv = ws + OFF_VV + nbase*DE + lane;
    #pragma unroll 4
    for (int i = 0; i < NN/NWAVE; ++i) {
        const int n = nbase + i;
        float a = vr[i*DE];
        float b = vv[i*DE];
        float4 wa0 = s_w1p[0][n], wa1 = s_w1p[1][n];
        float4 wb0 = s_w2p[0][n], wb1 = s_w2p[1][n];
        acc[0] += wa0.x*a + wb0.x*b;  acc[1] += wa0.y*a + wb0.y*b;
        acc[2] += wa0.z*a + wb0.z*b;  acc[3] += wa0.w*a + wb0.w*b;
        acc[4] += wa1.x*a + wb1.x*b;  acc[5] += wa1.y*a + wb1.y*b;
        acc[6] += wa1.z*a + wb1.z*b;  acc[7] += wa1.w*a + wb1.w*b;
    }
    #pragma unroll
    for (int c = 0; c < GC; ++c) s_part[wave][c][lane] = acc[c];
    __syncthreads();
    {
        const int c = tid >> 6;                   // GC == NWAVE == 8
        float r = 0.f;
        #pragma unroll
        for (int w = 0; w < NWAVE; ++w) r += s_part[w][c][lane];
        out[(c0 + c)*DE + lane] = r;
    }
}

extern "C" void kernel_launch(void* const* d_in, const int* in_sizes, int n_in,
                              void* d_out, int out_size, void* d_ws, size_t ws_size,
                              hipStream_t stream)
{
    const float* nc   = (const float*)d_in[0];
    const float* Wq_i = (const float*)d_in[1];
    const float* Wk_i = (const float*)d_in[2];
    const float* Wv_i = (const float*)d_in[3];
    const float* Wq_e = (const float*)d_in[4];
    const float* Wk_e = (const float*)d_in[5];
    const float* Wv_e = (const float*)d_in[6];
    const float* wg   = (const float*)d_in[7];
    const float* bg   = (const float*)d_in[8];
    float* out = (float*)d_out;
    float* ws  = (float*)d_ws;

    nce_precompute<<<NN/4, 256, 0, stream>>>(nc, Wq_i, Wk_i, Wv_i,
                                             Wq_e, Wk_e, Wv_e, wg, ws);
    nce_centre<<<NBLK, NT, 0, stream>>>(ws, bg, out);
}